// Round 5
// baseline (248.909 us; speedup 1.0000x reference)
//
#include <hip/hip_runtime.h>
#include <math.h>

#define OUT_NUM 1024
#define LUT_NUM 64
#define TBL     64
#define XROW    (LUT_NUM * 6)   // 384 floats of x per (br, o)
#define LSTRIDE 33              // float2 units per lut row (=66 dwords): 8B-aligned for all
                                // luts; ds_read_b64 lane->bank-pair map (L+p)%16 hits each
                                // pair exactly 4x = the b64 conflict-free floor

// (tanh(v)+1)/2 == sigmoid(2v) = 1/(1+exp(-2v)); rel err ~1e-6, threshold 1.8e-2.
__device__ __forceinline__ float softbit(float v) {
    return __builtin_amdgcn_rcpf(1.0f + __expf(-2.0f * v));
}

// Table lives in LDS (read per row), NOT in registers: live set = y[32]+x(6)+addr
// ~= 55 VGPR. (512,8) caps at 64 VGPR -> 8 waves/SIMD -> 4 blocks x 512 per CU ->
// all 1024 blocks resident in ONE round at 100% occupancy (grid supplies 8192 waves
// = 32/CU exactly). This is 2x the latency hiding of R3's grid-capped 4 waves/SIMD.
__global__ __launch_bounds__(512, 8)
void lut_fwd_kernel(const float* __restrict__ x,
                    const float* __restrict__ w,
                    float* __restrict__ out)
{
    __shared__ float2 wq[LUT_NUM * LSTRIDE];   // per lut: 32 pairs (even, odd-even)

    const int o = blockIdx.x;       // 0..1023
    const int t = threadIdx.x;      // 0..511

    // ---- Phase 1: stage w[o,:,:] (4096 floats), quantize, write (Ef, Df) pairs ----
    const float4* wrow4 = reinterpret_cast<const float4*>(w + (size_t)o * (LUT_NUM * TBL));
#pragma unroll
    for (int i = 0; i < 2; ++i) {
        const int f4   = t + 512 * i;      // 0..1023, coalesced
        const float4 v = wrow4[f4];
        const int lutc = f4 >> 4;          // 16 float4 per lut row
        const int m    = f4 & 15;          // covers pairs 2m, 2m+1
        const float s0 = softbit(v.x);
        const float s1 = softbit(v.y);
        const float s2 = softbit(v.z);
        const float s3 = softbit(v.w);
        float2* row = &wq[lutc * LSTRIDE];
        row[2*m]     = make_float2(s0, s1 - s0);   // (even, diff) for pair 2m
        row[2*m + 1] = make_float2(s2, s3 - s2);   // pair 2m+1
    }
    __syncthreads();

    const int lut = t & 63;          // lane i of each wave handles lut i
    const int rg  = t >> 6;          // wave 0..7 -> rows rg*4 .. rg*4+3
    const float2* row = &wq[lut * LSTRIDE];

    const float* xb = x + (size_t)o * XROW + lut * 6;    // 8B-aligned (lut*6 even)
    float* ob = out + (size_t)o * LUT_NUM + lut;

    // ---- Phase 2: 4 rows per thread; table streamed from LDS at level 0 ----
#pragma unroll 1   // keep live set bounded; 8 waves/SIMD hide the per-row load latency
    for (int j = 0; j < 4; ++j) {
        const int br = rg * 4 + j;   // 0..31
        const float2* xp = reinterpret_cast<const float2*>(
            xb + (size_t)br * (OUT_NUM * XROW));
        const float2 p01 = xp[0];
        const float2 p23 = xp[1];
        const float2 p45 = xp[2];

        float y[32];
#pragma unroll
        for (int p = 0; p < 32; ++p) {
            const float2 ed = row[p];            // ds_read_b64, conflict-free floor
            y[p] = fmaf(p01.x, ed.y, ed.x);      // level 0: single fma
        }
#pragma unroll
        for (int p = 0; p < 16; ++p)
            y[p] = fmaf(p01.y, y[2*p+1] - y[2*p], y[2*p]);
#pragma unroll
        for (int p = 0; p < 8; ++p)
            y[p] = fmaf(p23.x, y[2*p+1] - y[2*p], y[2*p]);
#pragma unroll
        for (int p = 0; p < 4; ++p)
            y[p] = fmaf(p23.y, y[2*p+1] - y[2*p], y[2*p]);
#pragma unroll
        for (int p = 0; p < 2; ++p)
            y[p] = fmaf(p45.x, y[2*p+1] - y[2*p], y[2*p]);
        const float res = fmaf(p45.y, y[1] - y[0], y[0]);

        // out[br, o, lut] — all 64 lanes write, contiguous 256B per wave
        ob[(size_t)br * (OUT_NUM * LUT_NUM)] = res;
    }
}

extern "C" void kernel_launch(void* const* d_in, const int* in_sizes, int n_in,
                              void* d_out, int out_size, void* d_ws, size_t ws_size,
                              hipStream_t stream)
{
    const float* x   = (const float*)d_in[0];   // [16,2,1024,384] f32
    const float* w   = (const float*)d_in[1];   // [1024,64,64]    f32
    float*       out = (float*)d_out;           // [16,2,1024,64]  f32
    lut_fwd_kernel<<<OUT_NUM, 512, 0, stream>>>(x, w, out);
}

// Round 6
// 135.633 us; speedup vs baseline: 1.8352x; 1.8352x over previous
//
#include <hip/hip_runtime.h>
#include <math.h>

#define OUT_NUM  1024
#define LUT_NUM  64
#define TBL      64
#define XROW     (LUT_NUM * 6)  // 384 floats of x per (br, o)
#define F4STRIDE 17             // float4 per lut row (16 data + 1 pad): every row base
                                // 16B-aligned (17*16B=272B); b128 bank pattern = the
                                // inherent 8-phase floor (256 dwords / 32 banks)

// (tanh(v)+1)/2 == sigmoid(2v) = 1/(1+exp(-2v)); rel err ~1e-6, threshold 1.8e-2.
__device__ __forceinline__ float softbit(float v) {
    return __builtin_amdgcn_rcpf(1.0f + __expf(-2.0f * v));
}

// Table in LDS, streamed per row with levels 0-2 FUSED so live set ~= y[8]+2*float4+
// temps+x(6)+addr ~= 50 VGPR. The asm launder below stops LICM/CSE from hoisting the
// 16 ds_read_b128 across rows (that hoist is what spilled R5: 64 table floats live).
// (512,8): <=64 VGPR -> 8 waves/SIMD -> 32 waves/CU -> all 1024 blocks resident.
__global__ __launch_bounds__(512, 8)
void lut_fwd_kernel(const float* __restrict__ x,
                    const float* __restrict__ w,
                    float* __restrict__ out)
{
    __shared__ float4 wq[LUT_NUM * F4STRIDE];   // per lut: 16 float4 = (E,D,E,D)...

    const int o = blockIdx.x;       // 0..1023
    const int t = threadIdx.x;      // 0..511

    // ---- Phase 1: stage w[o,:,:] (1024 float4), quantize, pack (E, D) pairs ----
    const float4* wrow4 = reinterpret_cast<const float4*>(w + (size_t)o * (LUT_NUM * TBL));
#pragma unroll
    for (int i = 0; i < 2; ++i) {
        const int f4   = t + 512 * i;     // 0..1023, coalesced
        const float4 v = wrow4[f4];
        const int lutc = f4 >> 4;         // 16 float4 per lut
        const int m    = f4 & 15;
        const float s0 = softbit(v.x);
        const float s1 = softbit(v.y);
        const float s2 = softbit(v.z);
        const float s3 = softbit(v.w);
        // (even, odd-even) for pairs 2m and 2m+1, one b128 write
        wq[lutc * F4STRIDE + m] = make_float4(s0, s1 - s0, s2, s3 - s2);
    }
    __syncthreads();

    const int lut = t & 63;          // lane i handles lut i
    const int rg  = t >> 6;          // wave 0..7 -> rows rg*4 .. rg*4+3
    const float4* rowbase = &wq[lut * F4STRIDE];

    const float* xb = x + (size_t)o * XROW + lut * 6;    // 8B-aligned (lut*6 even)
    float* ob = out + (size_t)o * LUT_NUM + lut;

    int   off = 0;      // always 0, but opaque to the compiler (laundered below)
    float res = 0.0f;

    // ---- Phase 2: 4 rows/thread; table re-streamed from LDS each row ----
#pragma unroll 1
    for (int j = 0; j < 4; ++j) {
        // launder: off is "modified" and "depends on" previous res -> the 16 LDS
        // reads below can be neither CSE'd nor hoisted across row iterations.
        asm volatile("" : "+v"(off) : "v"(res));
        const float4* rp = rowbase + off;

        const int br = rg * 4 + j;   // 0..31
        const float2* xp = reinterpret_cast<const float2*>(
            xb + (size_t)br * (OUT_NUM * XROW));
        const float2 p01 = xp[0];
        const float2 p23 = xp[1];
        const float2 p45 = xp[2];

        // levels 0-2 fused: consume 2 float4 (4 table pairs) -> one y2 value
        float y[8];
#pragma unroll
        for (int q = 0; q < 8; ++q) {
            const float4 a = rp[2*q];        // pairs 4q, 4q+1
            const float4 b = rp[2*q+1];      // pairs 4q+2, 4q+3
            const float t0 = fmaf(p01.x, a.y, a.x);
            const float t1 = fmaf(p01.x, a.w, a.z);
            const float t2 = fmaf(p01.x, b.y, b.x);
            const float t3 = fmaf(p01.x, b.w, b.z);
            const float u0 = fmaf(p01.y, t1 - t0, t0);
            const float u1 = fmaf(p01.y, t3 - t2, t2);
            y[q] = fmaf(p23.x, u1 - u0, u0);
        }
        // levels 3-5 in registers
#pragma unroll
        for (int q = 0; q < 4; ++q) y[q] = fmaf(p23.y, y[2*q+1] - y[2*q], y[2*q]);
#pragma unroll
        for (int q = 0; q < 2; ++q) y[q] = fmaf(p45.x, y[2*q+1] - y[2*q], y[2*q]);
        res = fmaf(p45.y, y[1] - y[0], y[0]);

        // out[br, o, lut] — 64 lanes write contiguous 256B
        ob[(size_t)br * (OUT_NUM * LUT_NUM)] = res;
    }
}

extern "C" void kernel_launch(void* const* d_in, const int* in_sizes, int n_in,
                              void* d_out, int out_size, void* d_ws, size_t ws_size,
                              hipStream_t stream)
{
    const float* x   = (const float*)d_in[0];   // [16,2,1024,384] f32
    const float* w   = (const float*)d_in[1];   // [1024,64,64]    f32
    float*       out = (float*)d_out;           // [16,2,1024,64]  f32
    lut_fwd_kernel<<<OUT_NUM, 512, 0, stream>>>(x, w, out);
}

// Round 7
// 93.666 us; speedup vs baseline: 2.6574x; 1.4481x over previous
//
#include <hip/hip_runtime.h>
#include <math.h>

#define OUT_NUM 1024
#define LUT_NUM 64
#define TBL     64
#define XROW    (LUT_NUM * 6)   // 384 floats of x per (br, o)
#define WSTRIDE 68              // dwords per lut row: 16B-aligned rows (272B); for
                                // ds_read_b128 granule = (17L+q)%8 -> conflict-free

// (tanh(v)+1)/2 == sigmoid(2v) = 1/(1+exp(-2v)); rel err ~1e-6, threshold 1.8e-2.
__device__ __forceinline__ float softbit(float v) {
    return __builtin_amdgcn_rcpf(1.0f + __expf(-2.0f * v));
}

// R3 structure (proven no-spill) + x software pipeline.
// Live set: evn[32]+dif[32] (64) + cur x (6) + next x (6) + y[32] + addr ~= 116 < 128.
// (256,4): 4 waves/SIMD, 4 blocks/CU -> all 1024 blocks resident, one round.
__global__ __launch_bounds__(256, 4)
void lut_fwd_kernel(const float* __restrict__ x,
                    const float* __restrict__ w,
                    float* __restrict__ out)
{
    __shared__ __align__(16) float wq[LUT_NUM * WSTRIDE]; // per lut: [0..31]=evn, [32..63]=dif

    const int o = blockIdx.x;       // 0..1023
    const int t = threadIdx.x;      // 0..255

    // ---- Phase 1: stage w[o,:,:] (4096 floats), quantize, split (evn, dif) ----
    const float4* wrow4 = reinterpret_cast<const float4*>(w + (size_t)o * (LUT_NUM * TBL));
#pragma unroll
    for (int i = 0; i < 4; ++i) {
        const int f4   = t + 256 * i;     // 0..1023, coalesced
        const float4 v = wrow4[f4];
        const int lutc = f4 >> 4;         // 16 float4 per lut
        const int m    = f4 & 15;         // covers pairs 2m, 2m+1
        const float s0 = softbit(v.x);
        const float s1 = softbit(v.y);
        const float s2 = softbit(v.z);
        const float s3 = softbit(v.w);
        float* row = &wq[lutc * WSTRIDE];
        row[2*m]      = s0;
        row[32 + 2*m] = s1 - s0;          // level-0 diff precomputed
        row[2*m + 1]  = s2;
        row[33 + 2*m] = s3 - s2;
    }
    __syncthreads();

    const int lut = t & 63;          // lane i handles lut i
    const int rg  = t >> 6;          // wave 0..3 -> rows rg*8 .. rg*8+7

    // ---- table into registers once, via 16 conflict-free ds_read_b128 ----
    float evn[32], dif[32];
    const float4* rv = reinterpret_cast<const float4*>(&wq[lut * WSTRIDE]);
#pragma unroll
    for (int q = 0; q < 8; ++q) {
        const float4 e = rv[q];
        const float4 d = rv[8 + q];
        evn[4*q] = e.x; evn[4*q+1] = e.y; evn[4*q+2] = e.z; evn[4*q+3] = e.w;
        dif[4*q] = d.x; dif[4*q+1] = d.y; dif[4*q+2] = d.z; dif[4*q+3] = d.w;
    }

    const float* xb = x + (size_t)o * XROW + lut * 6;    // 8B-aligned (lut*6 even)
    float* ob = out + (size_t)o * LUT_NUM + lut;
    const int br0 = rg * 8;

    // ---- Phase 2: 8 rows, 1-row x prefetch pipeline ----
    const float2* xp0 = reinterpret_cast<const float2*>(xb + (size_t)br0 * (OUT_NUM * XROW));
    float2 c0 = xp0[0], c1 = xp0[1], c2 = xp0[2];

#pragma unroll 2   // bounded hoisting: full unroll would hoist 48 load regs -> spill
    for (int j = 0; j < 8; ++j) {
        // prefetch row j+1 (clamped to &7: last iter re-reads row 0, harmless L2 hit)
        const int jn = (j + 1) & 7;
        const float2* np = reinterpret_cast<const float2*>(
            xb + (size_t)(br0 + jn) * (OUT_NUM * XROW));
        const float2 n0 = np[0];
        const float2 n1 = np[1];
        const float2 n2 = np[2];

        // tree for current row (loads above are independent -> overlap with this)
        float y[32];
#pragma unroll
        for (int p = 0; p < 32; ++p)
            y[p] = fmaf(c0.x, dif[p], evn[p]);           // level 0: single fma
#pragma unroll
        for (int p = 0; p < 16; ++p)
            y[p] = fmaf(c0.y, y[2*p+1] - y[2*p], y[2*p]);
#pragma unroll
        for (int p = 0; p < 8; ++p)
            y[p] = fmaf(c1.x, y[2*p+1] - y[2*p], y[2*p]);
#pragma unroll
        for (int p = 0; p < 4; ++p)
            y[p] = fmaf(c1.y, y[2*p+1] - y[2*p], y[2*p]);
#pragma unroll
        for (int p = 0; p < 2; ++p)
            y[p] = fmaf(c2.x, y[2*p+1] - y[2*p], y[2*p]);
        const float res = fmaf(c2.y, y[1] - y[0], y[0]);

        // out[br, o, lut] — 64 lanes write contiguous 256B
        ob[(size_t)(br0 + j) * (OUT_NUM * LUT_NUM)] = res;

        c0 = n0; c1 = n1; c2 = n2;   // rotate pipeline
    }
}

extern "C" void kernel_launch(void* const* d_in, const int* in_sizes, int n_in,
                              void* d_out, int out_size, void* d_ws, size_t ws_size,
                              hipStream_t stream)
{
    const float* x   = (const float*)d_in[0];   // [16,2,1024,384] f32
    const float* w   = (const float*)d_in[1];   // [1024,64,64]    f32
    float*       out = (float*)d_out;           // [16,2,1024,64]  f32
    lut_fwd_kernel<<<OUT_NUM, 256, 0, stream>>>(x, w, out);
}

// Round 8
// 92.938 us; speedup vs baseline: 2.6782x; 1.0078x over previous
//
#include <hip/hip_runtime.h>
#include <math.h>

#define OUT_NUM 1024
#define LUT_NUM 64
#define TBL     64
#define XROWD   384             // dwords of x per (br, o) row segment
#define WSTRIDE 68              // dwords per lut table row (16B-aligned, b128 conflict-free)
#define BUFD    3072            // dwords per x stage buffer: 8 rows * 384

// (tanh(v)+1)/2 == sigmoid(2v) = 1/(1+exp(-2v)); rel err ~1e-6, threshold 1.8e-2.
__device__ __forceinline__ float softbit(float v) {
    return __builtin_amdgcn_rcpf(1.0f + __expf(-2.0f * v));
}

// Table in registers (proven R3 path), LDS reused as a double-buffered x stage:
// x arrives via 3 global_load_dwordx4/thread/batch (16B/lane, 1KB/wave-instr)
// and fans out to compute lanes via ds_read_b64 (2-way banks = free).
// Live ~= evn/dif(64)+landing(12)+y(32)+misc -> <128 VGPR; (256,4): 4 blocks/CU,
// LDS 24.6KB, all 1024 blocks resident in one round.
__global__ __launch_bounds__(256, 4)
void lut_fwd_kernel(const float* __restrict__ x,
                    const float* __restrict__ w,
                    float* __restrict__ out)
{
    __shared__ __align__(16) float smem[2 * BUFD];   // 24576 B; table (17408 B) overlays it

    const int o = blockIdx.x;       // 0..1023
    const int t = threadIdx.x;      // 0..255

    // ---- Phase 1: stage w[o,:,:], quantize, split (evn, dif) into LDS table ----
    {
        float* wq = smem;           // table overlay, consumed before x staging begins
        const float4* wrow4 = reinterpret_cast<const float4*>(w + (size_t)o * (LUT_NUM * TBL));
#pragma unroll
        for (int i = 0; i < 4; ++i) {
            const int f4   = t + 256 * i;     // 0..1023, coalesced
            const float4 v = wrow4[f4];
            const int lutc = f4 >> 4;         // 16 float4 per lut
            const int m    = f4 & 15;         // covers pairs 2m, 2m+1
            const float s0 = softbit(v.x);
            const float s1 = softbit(v.y);
            const float s2 = softbit(v.z);
            const float s3 = softbit(v.w);
            float* row = &wq[lutc * WSTRIDE];
            row[2*m]      = s0;
            row[32 + 2*m] = s1 - s0;          // level-0 diff precomputed
            row[2*m + 1]  = s2;
            row[33 + 2*m] = s3 - s2;
        }
    }
    __syncthreads();

    const int lut = t & 63;          // lane i handles lut i
    const int r0  = t >> 6;          // wave id 0..3 -> rows {r0, r0+4} of each batch

    // ---- table into registers once (16x conflict-free ds_read_b128) ----
    float evn[32], dif[32];
    {
        const float4* rv = reinterpret_cast<const float4*>(&smem[lut * WSTRIDE]);
#pragma unroll
        for (int q = 0; q < 8; ++q) {
            const float4 e = rv[q];
            const float4 d = rv[8 + q];
            evn[4*q] = e.x; evn[4*q+1] = e.y; evn[4*q+2] = e.z; evn[4*q+3] = e.w;
            dif[4*q] = d.x; dif[4*q+1] = d.y; dif[4*q+2] = d.z; dif[4*q+3] = d.w;
        }
    }
    __syncthreads();                 // everyone done with table -> LDS becomes x stage

    const float4* xg4   = reinterpret_cast<const float4*>(x);
    float4*       xbuf4 = reinterpret_cast<float4*>(smem);

    // ---- stage batch 0 (rows 0..7): 3 float4 per thread, 16B/lane coalesced ----
#pragma unroll
    for (int i = 0; i < 3; ++i) {
        const int f = t + 256 * i;           // 0..767 float4 within batch
        const int k = f / 96;                // row in batch (96 float4 per row)
        const int c = f - 96 * k;
        xbuf4[f] = xg4[((size_t)k * OUT_NUM + o) * 96 + c];
    }
    __syncthreads();

    float* ob = out + (size_t)o * LUT_NUM + lut;

    // ---- Phase 2: 4 batches of 8 rows, double-buffered ----
#pragma unroll 1
    for (int b = 0; b < 4; ++b) {
        // prefetch batch b+1 into registers (issued before compute -> overlaps)
        float4 nf0, nf1, nf2;
        if (b < 3) {
#pragma unroll
            for (int i = 0; i < 3; ++i) {
                const int f = t + 256 * i;
                const int k = f / 96;
                const int c = f - 96 * k;
                const float4 v = xg4[((size_t)(8*(b+1) + k) * OUT_NUM + o) * 96 + c];
                if (i == 0) nf0 = v; else if (i == 1) nf1 = v; else nf2 = v;
            }
        }

        // compute 2 outputs from current buffer
        const float* cb = smem + (b & 1) * BUFD;
#pragma unroll
        for (int s = 0; s < 2; ++s) {
            const int r  = r0 + 4 * s;       // row in batch, 0..7
            const int br = 8 * b + r;        // 0..31
            const float2* xp = reinterpret_cast<const float2*>(cb + r * XROWD + lut * 6);
            const float2 p01 = xp[0];        // ds_read_b64, 2-way banks = free
            const float2 p23 = xp[1];
            const float2 p45 = xp[2];

            float y[32];
#pragma unroll
            for (int p = 0; p < 32; ++p)
                y[p] = fmaf(p01.x, dif[p], evn[p]);
#pragma unroll
            for (int p = 0; p < 16; ++p)
                y[p] = fmaf(p01.y, y[2*p+1] - y[2*p], y[2*p]);
#pragma unroll
            for (int p = 0; p < 8; ++p)
                y[p] = fmaf(p23.x, y[2*p+1] - y[2*p], y[2*p]);
#pragma unroll
            for (int p = 0; p < 4; ++p)
                y[p] = fmaf(p23.y, y[2*p+1] - y[2*p], y[2*p]);
#pragma unroll
            for (int p = 0; p < 2; ++p)
                y[p] = fmaf(p45.x, y[2*p+1] - y[2*p], y[2*p]);
            const float res = fmaf(p45.y, y[1] - y[0], y[0]);

            ob[(size_t)br * (OUT_NUM * LUT_NUM)] = res;   // 256B contiguous per wave
        }

        // drain prefetch into the other buffer, then barrier
        if (b < 3) {
            float4* nb = xbuf4 + ((b + 1) & 1) * (BUFD / 4);
            nb[t]       = nf0;               // ds_write_b128 at the 8-phase floor
            nb[t + 256] = nf1;
            nb[t + 512] = nf2;
        }
        __syncthreads();
    }
}

extern "C" void kernel_launch(void* const* d_in, const int* in_sizes, int n_in,
                              void* d_out, int out_size, void* d_ws, size_t ws_size,
                              hipStream_t stream)
{
    const float* x   = (const float*)d_in[0];   // [16,2,1024,384] f32
    const float* w   = (const float*)d_in[1];   // [1024,64,64]    f32
    float*       out = (float*)d_out;           // [16,2,1024,64]  f32
    lut_fwd_kernel<<<OUT_NUM, 256, 0, stream>>>(x, w, out);
}

// Round 9
// 92.766 us; speedup vs baseline: 2.6832x; 1.0019x over previous
//
#include <hip/hip_runtime.h>
#include <math.h>

#define OUT_NUM 1024
#define LUT_NUM 64
#define TBL     64
#define XROWD   384              // dwords of x per (br, o) row
#define WSTRIDE 68               // dwords per lut table row (16B-aligned, b128 conflict-free)
#define BUFD    3072             // dwords per x stage buffer (8 rows * 384)
#define TBLD    (LUT_NUM * WSTRIDE)   // 4352 dwords = 17408 B
// LDS map: table [0, TBLD) ; buffer A [TBLD, TBLD+BUFD) ; buffer B reuses [0, BUFD)
// after the table has been consumed (barrier2 guarantees it).

// (tanh(v)+1)/2 == sigmoid(2v) = 1/(1+exp(-2v)); rel err ~1e-6, threshold 1.8e-2.
__device__ __forceinline__ float softbit(float v) {
    return __builtin_amdgcn_rcpf(1.0f + __expf(-2.0f * v));
}

__global__ __launch_bounds__(256, 4)
void lut_fwd_kernel(const float* __restrict__ x,
                    const float* __restrict__ w,
                    float* __restrict__ out)
{
    __shared__ __align__(16) float smem[TBLD + BUFD];   // 29696 B -> 4 blocks/CU ok

    const int o = blockIdx.x;       // 0..1023
    const int t = threadIdx.x;      // 0..255

    const float4* xg4 = reinterpret_cast<const float4*>(x);

    // ---- issue batch-0 x loads FIRST (12 KB/block in flight from cycle ~0) ----
    const int k0 = t / 96 /* row in batch */, c0 = t - 96 * k0;
    const int f1 = t + 256, k1 = f1 / 96, c1 = f1 - 96 * k1;
    const int f2 = t + 512, k2 = f2 / 96, c2 = f2 - 96 * k2;
    const float4 a0 = xg4[((size_t)k0 * OUT_NUM + o) * 96 + c0];
    const float4 a1 = xg4[((size_t)k1 * OUT_NUM + o) * 96 + c1];
    const float4 a2 = xg4[((size_t)k2 * OUT_NUM + o) * 96 + c2];

    // ---- Phase 1: w[o,:,:] -> quantize -> (evn,dif) table in LDS [0,TBLD) ----
    const float4* wrow4 = reinterpret_cast<const float4*>(w + (size_t)o * (LUT_NUM * TBL));
#pragma unroll
    for (int i = 0; i < 4; ++i) {
        const int f4   = t + 256 * i;     // 0..1023, coalesced
        const float4 v = wrow4[f4];
        const int lutc = f4 >> 4;
        const int m    = f4 & 15;
        const float s0 = softbit(v.x);
        const float s1 = softbit(v.y);
        const float s2 = softbit(v.z);
        const float s3 = softbit(v.w);
        float* row = &smem[lutc * WSTRIDE];
        row[2*m]      = s0;
        row[32 + 2*m] = s1 - s0;
        row[2*m + 1]  = s2;
        row[33 + 2*m] = s3 - s2;
    }
    __syncthreads();                      // barrier 1: table visible

    const int lut = t & 63;
    const int r0  = t >> 6;               // wave id -> rows {r0, r0+4} of each batch

    // ---- table -> registers (16x conflict-free ds_read_b128) ----
    float evn[32], dif[32];
    {
        const float4* rv = reinterpret_cast<const float4*>(&smem[lut * WSTRIDE]);
#pragma unroll
        for (int q = 0; q < 8; ++q) {
            const float4 e = rv[q];
            const float4 d = rv[8 + q];
            evn[4*q] = e.x; evn[4*q+1] = e.y; evn[4*q+2] = e.z; evn[4*q+3] = e.w;
            dif[4*q] = d.x; dif[4*q+1] = d.y; dif[4*q+2] = d.z; dif[4*q+3] = d.w;
        }
    }

    // ---- stage batch 0 into buffer A (disjoint from table -> no extra barrier) ----
    {
        float4* A = reinterpret_cast<float4*>(smem + TBLD);
        A[t]       = a0;                  // ds_write_b128, 8-phase floor
        A[t + 256] = a1;
        A[t + 512] = a2;
    }
    __syncthreads();                      // barrier 2: batch 0 ready; table consumed

    float* ob = out + (size_t)o * LUT_NUM + lut;

    // buffer base for batch b: A=[TBLD,) for even b, B=[0,) for odd b
#pragma unroll 1
    for (int b = 0; b < 4; ++b) {
        // prefetch batch b+1 into registers (overlaps compute below)
        float4 nf0, nf1, nf2;
        if (b < 3) {
            const size_t rb = (size_t)(8 * (b + 1));
            nf0 = xg4[((rb + k0) * OUT_NUM + o) * 96 + c0];
            nf1 = xg4[((rb + k1) * OUT_NUM + o) * 96 + c1];
            nf2 = xg4[((rb + k2) * OUT_NUM + o) * 96 + c2];
        }

        const float* cb = smem + ((b & 1) ? 0 : TBLD);
#pragma unroll
        for (int s = 0; s < 2; ++s) {
            const int r  = r0 + 4 * s;    // row in batch
            const int br = 8 * b + r;     // 0..31
            const float2* xp = reinterpret_cast<const float2*>(cb + r * XROWD + lut * 6);
            const float2 p01 = xp[0];     // ds_read_b64, 2-way banks = free
            const float2 p23 = xp[1];
            const float2 p45 = xp[2];

            float y[32];
#pragma unroll
            for (int p = 0; p < 32; ++p)
                y[p] = fmaf(p01.x, dif[p], evn[p]);
#pragma unroll
            for (int p = 0; p < 16; ++p)
                y[p] = fmaf(p01.y, y[2*p+1] - y[2*p], y[2*p]);
#pragma unroll
            for (int p = 0; p < 8; ++p)
                y[p] = fmaf(p23.x, y[2*p+1] - y[2*p], y[2*p]);
#pragma unroll
            for (int p = 0; p < 4; ++p)
                y[p] = fmaf(p23.y, y[2*p+1] - y[2*p], y[2*p]);
#pragma unroll
            for (int p = 0; p < 2; ++p)
                y[p] = fmaf(p45.x, y[2*p+1] - y[2*p], y[2*p]);
            const float res = fmaf(p45.y, y[1] - y[0], y[0]);

            ob[(size_t)br * (OUT_NUM * LUT_NUM)] = res;   // 256B contiguous per wave
        }

        if (b < 3) {
            float4* nb = reinterpret_cast<float4*>(smem + ((b & 1) ? TBLD : 0));
            nb[t]       = nf0;
            nb[t + 256] = nf1;
            nb[t + 512] = nf2;
            __syncthreads();              // batch b+1 ready (no barrier after last batch)
        }
    }
}

extern "C" void kernel_launch(void* const* d_in, const int* in_sizes, int n_in,
                              void* d_out, int out_size, void* d_ws, size_t ws_size,
                              hipStream_t stream)
{
    const float* x   = (const float*)d_in[0];   // [16,2,1024,384] f32
    const float* w   = (const float*)d_in[1];   // [1024,64,64]    f32
    float*       out = (float*)d_out;           // [16,2,1024,64]  f32
    lut_fwd_kernel<<<OUT_NUM, 256, 0, stream>>>(x, w, out);
}